// Round 8
// baseline (853.026 us; speedup 1.0000x reference)
//
#include <hip/hip_runtime.h>
#include <math.h>

// ---------------------------------------------------------------------------
// SparseMoE — FULL-FP32 discriminating probe for MI355X (gfx950).
// B=8 S=4096 D=256 F=512 E=8 TOP_K=2, all inputs fp32, output fp32.
// No bf16 anywhere: GEMM1/GELU/GEMM2/residual/LN all exact fp32 (VALU).
// Router: fp64 deterministic, plain top-2 (ties -> lowest index).
// Purpose: if this passes, the 0.19 error was a latent bf16-path bug;
// if it fails ~0.19, router selection is proven to be the cause.
// ws usage: ~1.1 MB. Fully deterministic (graph replay bit-stable).
// ---------------------------------------------------------------------------

#define B_ 8
#define S_ 4096
#define D_ 256
#define F_ 512
#define E_ 8

// ---------------------------------------------------------------------------
// 1a) partial[b*64+c][d] = fp64 sum of 64 consecutive s-rows (deterministic)
// ---------------------------------------------------------------------------
__global__ void k_reduce1(const float* __restrict__ x,
                          double* __restrict__ partial) {
    int b = blockIdx.x >> 6;
    int c = blockIdx.x & 63;
    int d = threadIdx.x;              // 256 threads = D
    const float* p = x + ((size_t)(b * S_ + c * 64) * D_ + d);
    double acc = 0.0;
    #pragma unroll 8
    for (int i = 0; i < 64; ++i) acc += (double)p[(size_t)i * D_];
    partial[(size_t)blockIdx.x * D_ + d] = acc;
}

// 1b) xsum[b][d] = fp64 sum_c partial[b*64+c][d]  (fixed order)
__global__ void k_reduce2(const double* __restrict__ partial,
                          double* __restrict__ xsum) {
    int b = blockIdx.x;
    int d = threadIdx.x;
    double acc = 0.0;
    #pragma unroll 8
    for (int c = 0; c < 64; ++c) acc += partial[(size_t)(b * 64 + c) * D_ + d];
    xsum[b * D_ + d] = acc;
}

// ---------------------------------------------------------------------------
// 2) Router, FP64: logits -> softmax -> capacity rescale -> softmax
//    -> top2 (ties -> lowest) -> 2-way softmax. route[b]={e0,e1,w0,w1}.
// ---------------------------------------------------------------------------
__global__ void k_router(const double* __restrict__ xsum,
                         const float* __restrict__ Wr,
                         const float* __restrict__ br,
                         float* __restrict__ route) {
    __shared__ double lg[64];
    int t = threadIdx.x;              // 64 threads
    int b = t >> 3, e = t & 7;
    double acc = 0.0;
    for (int d = 0; d < D_; ++d)
        acc += (xsum[b * D_ + d] * (1.0 / (double)S_)) * (double)Wr[d * E_ + e];
    lg[t] = acc + (double)br[e];
    __syncthreads();
    if (t == 0) {
        double rw[8][8];
        for (int bb = 0; bb < 8; ++bb) {
            double m = -1e300;
            for (int ee = 0; ee < 8; ++ee) m = fmax(m, lg[bb * 8 + ee]);
            double s = 0.0;
            for (int ee = 0; ee < 8; ++ee) { double p = exp(lg[bb * 8 + ee] - m); rw[bb][ee] = p; s += p; }
            for (int ee = 0; ee < 8; ++ee) rw[bb][ee] /= s;
        }
        const double capacity = 5120.0;   // ceil(N * 1.25 / E)
        double scale[8];
        for (int ee = 0; ee < 8; ++ee) {
            double load = 0.0;
            for (int bb = 0; bb < 8; ++bb) load += rw[bb][ee];
            load *= 4096.0;               // * (N/B)
            scale[ee] = load > capacity ? capacity / load : 1.0;
        }
        for (int bb = 0; bb < 8; ++bb) {
            double v[8];
            double m = -1e300;
            for (int ee = 0; ee < 8; ++ee) { v[ee] = rw[bb][ee] * scale[ee]; m = fmax(m, v[ee]); }
            double s = 0.0;
            for (int ee = 0; ee < 8; ++ee) { v[ee] = exp(v[ee] - m); s += v[ee]; }
            for (int ee = 0; ee < 8; ++ee) v[ee] /= s;
            int i1 = 0;
            for (int ee = 1; ee < 8; ++ee) if (v[ee] > v[i1]) i1 = ee;
            int i2 = (i1 == 0) ? 1 : 0;
            for (int ee = 0; ee < 8; ++ee) { if (ee == i1) continue; if (v[ee] > v[i2]) i2 = ee; }
            double d21 = v[i2] - v[i1];
            double ed = exp(d21);
            double w1 = 1.0 / (1.0 + ed);
            double w2 = ed * w1;
            route[bb * 4 + 0] = (float)i1;
            route[bb * 4 + 1] = (float)i2;
            route[bb * 4 + 2] = (float)w1;
            route[bb * 4 + 3] = (float)w2;
        }
    }
}

// ---------------------------------------------------------------------------
// 3) Main fused kernel, FULL FP32 (no MFMA, no bf16):
//    per block = (batch, 32-token tile); 1024 blocks x 256 threads.
//    For each of the 2 experts: for each 64-wide F-block:
//      GEMM1 (X(LDS) @ W1(global, coalesced)) -> exact GELU * w -> Hsh(LDS)
//      GEMM2 (Hsh @ W2(global, coalesced)) -> fp32 accumulators.
//    Epilogue: in-place residual into Xs, then LayerNorm, fp32 out.
//    Thread map: rg = t>>6 (4 row groups x 8 rows), c0 = t&63.
// ---------------------------------------------------------------------------
__launch_bounds__(256, 2)
__global__ void k_moe32(const float* __restrict__ xf,   // [B][S][D]
                        const float* __restrict__ W1,   // [E][D][F]
                        const float* __restrict__ W2,   // [E][F][D]
                        const float* __restrict__ b1,   // [E][F]
                        const float* __restrict__ b2,   // [E][D]
                        const float* __restrict__ gamma,
                        const float* __restrict__ beta,
                        const float* __restrict__ route,
                        float* __restrict__ out) {
    __shared__ __align__(16) float Xs[32][260];   // X tile / pre-LN buffer
    __shared__ __align__(16) float Hsh[32][68];   // H f-block (w-scaled)
    __shared__ float gb[256], bb[256];

    const int t = threadIdx.x;
    const int rg = t >> 6;            // row group 0..3
    const int c0 = t & 63;            // f-lane / col-lane
    const int b = blockIdx.x & 7;     // XCD swizzle: batch -> XCD
    const int m0 = (blockIdx.x >> 3) * 32;

    gb[t] = gamma[t];
    bb[t] = beta[t];

    // stage X tile [32][256] (coalesced float4)
    #pragma unroll
    for (int rr = 0; rr < 8; ++rr) {
        int row = rg * 8 + rr;
        *(float4*)&Xs[row][c0 * 4] =
            *(const float4*)&xf[(size_t)(b * S_ + m0 + row) * D_ + c0 * 4];
    }

    const int e0i = (int)route[b * 4 + 0];
    const int e1i = (int)route[b * 4 + 1];
    const float w0 = route[b * 4 + 2];
    const float w1 = route[b * 4 + 3];
    const int eidx[2] = { e0i, e1i };
    const float wgt[2] = { w0, w1 };

    float Yacc[8][4];
    #pragma unroll
    for (int rr = 0; rr < 8; ++rr)
        #pragma unroll
        for (int cj = 0; cj < 4; ++cj) Yacc[rr][cj] = 0.f;

    for (int sl = 0; sl < 2; ++sl) {
        const int e = eidx[sl];
        const float w = wgt[sl];
        const float* w1base = W1 + (size_t)e * D_ * F_ + c0;
        const float* w2base = W2 + (size_t)e * F_ * D_ + c0;

        for (int fb = 0; fb < 8; ++fb) {
            __syncthreads();   // prev GEMM2 done with Hsh; Xs staged (fb=0)

            // ---- GEMM1: hacc[rr] = sum_d Xs[row][d] * W1[d][fb*64+c0] ----
            float hacc[8];
            #pragma unroll
            for (int rr = 0; rr < 8; ++rr) hacc[rr] = 0.f;
            const float* w1p = w1base + fb * 64;
            for (int d = 0; d < D_; d += 4) {
                float a0 = w1p[(size_t)(d + 0) * F_];
                float a1 = w1p[(size_t)(d + 1) * F_];
                float a2 = w1p[(size_t)(d + 2) * F_];
                float a3 = w1p[(size_t)(d + 3) * F_];
                #pragma unroll
                for (int rr = 0; rr < 8; ++rr) {
                    float4 xv = *(const float4*)&Xs[rg * 8 + rr][d];
                    hacc[rr] += xv.x * a0 + xv.y * a1 + xv.z * a2 + xv.w * a3;
                }
            }

            // ---- exact GELU (+b1) * routing weight -> Hsh ----
            float bias1 = b1[e * F_ + fb * 64 + c0];
            #pragma unroll
            for (int rr = 0; rr < 8; ++rr) {
                float v = hacc[rr] + bias1;
                float h = 0.5f * v * (1.0f + erff(v * 0.70710678118654752f));
                Hsh[rg * 8 + rr][c0] = w * h;
            }
            __syncthreads();   // Hsh visible

            // ---- GEMM2: Yacc[rr][cj] += sum_f Hsh[row][f] * W2[f][c] ----
            const float* w2p = w2base + (size_t)(fb * 64) * D_;
            for (int f = 0; f < 64; f += 4) {
                float a[4][4];
                #pragma unroll
                for (int ff = 0; ff < 4; ++ff) {
                    const float* wp = w2p + (size_t)(f + ff) * D_;
                    a[ff][0] = wp[0];   a[ff][1] = wp[64];
                    a[ff][2] = wp[128]; a[ff][3] = wp[192];
                }
                #pragma unroll
                for (int rr = 0; rr < 8; ++rr) {
                    float4 hv = *(const float4*)&Hsh[rg * 8 + rr][f];
                    #pragma unroll
                    for (int cj = 0; cj < 4; ++cj)
                        Yacc[rr][cj] += hv.x * a[0][cj] + hv.y * a[1][cj]
                                      + hv.z * a[2][cj] + hv.w * a[3][cj];
                }
            }
        }
    }

    // ---- Epilogue: in-place residual into Xs (fp32) ----
    __syncthreads();   // all waves done reading Xs/Hsh
    float bias2[4];
    #pragma unroll
    for (int cj = 0; cj < 4; ++cj)
        bias2[cj] = w0 * b2[e0i * D_ + c0 + cj * 64] +
                    w1 * b2[e1i * D_ + c0 + cj * 64];
    #pragma unroll
    for (int rr = 0; rr < 8; ++rr) {
        int row = rg * 8 + rr;
        #pragma unroll
        for (int cj = 0; cj < 4; ++cj) {
            int cc = c0 + cj * 64;
            Xs[row][cc] = Yacc[rr][cj] + bias2[cj] + Xs[row][cc];
        }
    }
    __syncthreads();

    // ---- LayerNorm (fp32): 8 threads per row, 32 elems each ----
    {
        int row = t >> 3, q = t & 7;
        float sum = 0.f, sq = 0.f;
        #pragma unroll
        for (int j = 0; j < 32; ++j) {
            float v = Xs[row][q * 32 + j];
            sum += v; sq += v * v;
        }
        sum += __shfl_xor(sum, 1); sq += __shfl_xor(sq, 1);
        sum += __shfl_xor(sum, 2); sq += __shfl_xor(sq, 2);
        sum += __shfl_xor(sum, 4); sq += __shfl_xor(sq, 4);
        float mu = sum * (1.0f / 256.0f);
        float var = sq * (1.0f / 256.0f) - mu * mu;
        float rstd = rsqrtf(var + 1e-5f);
        float* op = out + (size_t)(b * S_ + m0 + row) * D_ + q * 32;
        #pragma unroll
        for (int j4 = 0; j4 < 32; j4 += 4) {
            float4 v = *(const float4*)&Xs[row][q * 32 + j4];
            int db = q * 32 + j4;
            float4 o;
            o.x = (v.x - mu) * rstd * gb[db + 0] + bb[db + 0];
            o.y = (v.y - mu) * rstd * gb[db + 1] + bb[db + 1];
            o.z = (v.z - mu) * rstd * gb[db + 2] + bb[db + 2];
            o.w = (v.w - mu) * rstd * gb[db + 3] + bb[db + 3];
            *(float4*)(op + j4) = o;
        }
    }
}

// ---------------------------------------------------------------------------
extern "C" void kernel_launch(void* const* d_in, const int* in_sizes, int n_in,
                              void* d_out, int out_size, void* d_ws, size_t ws_size,
                              hipStream_t stream) {
    const float* x     = (const float*)d_in[0];
    const float* Wr    = (const float*)d_in[1];
    const float* br    = (const float*)d_in[2];
    const float* W1    = (const float*)d_in[3];
    const float* b1    = (const float*)d_in[4];
    const float* W2    = (const float*)d_in[5];
    const float* b2    = (const float*)d_in[6];
    const float* gamma = (const float*)d_in[7];
    const float* beta  = (const float*)d_in[8];
    float* out = (float*)d_out;

    char* ws = (char*)d_ws;
    double* partial = (double*)ws;                       // 1 MB (512x256 f64)
    double* xsum  = (double*)(ws + 1048576);             // 16 KB
    float* route  = (float*)(ws + 1048576 + 16384);      // 128 B
    // total ws usage: ~1.1 MB

    hipLaunchKernelGGL(k_reduce1, dim3(512), dim3(256), 0, stream, x, partial);
    hipLaunchKernelGGL(k_reduce2, dim3(8), dim3(256), 0, stream, partial, xsum);
    hipLaunchKernelGGL(k_router, dim3(1), dim3(64), 0, stream, xsum, Wr, br, route);
    hipLaunchKernelGGL(k_moe32, dim3(1024), dim3(256), 0, stream,
                       x, W1, W2, b1, b2, gamma, beta, route, out);
}

// Round 10
// 312.256 us; speedup vs baseline: 2.7318x; 2.7318x over previous
//
#include <hip/hip_runtime.h>
#include <math.h>

// ---------------------------------------------------------------------------
// SparseMoE — MFMA kernel on the r8-proven skeleton, MI355X (gfx950).
// B=8 S=4096 D=256 F=512 E=8 TOP_K=2, fp32 in/out.
// Key change vs failed r3-r7/r9 variants: NO staged-LDS W buffers, no
// 4-barrier K-loop. B-fragments load directly from global (bf16 W mirrors);
// A-fragments from a once-staged bf16 X tile in LDS; single H handoff via
// LDS with the r8-proven 2-barrier pattern. Router fp64 deterministic.
// ws ~5.1 MB. Fully deterministic.
// ---------------------------------------------------------------------------

#define B_ 8
#define S_ 4096
#define D_ 256
#define F_ 512
#define E_ 8

typedef short bf16x8 __attribute__((ext_vector_type(8)));
typedef float f32x4 __attribute__((ext_vector_type(4)));

static __device__ __forceinline__ unsigned short f2bf(float f) {
    union { float f; unsigned int i; } v; v.f = f;
    unsigned int x = v.i;
    return (unsigned short)((x + 0x7fffu + ((x >> 16) & 1u)) >> 16);  // RNE
}
static __device__ __forceinline__ float bf2f(unsigned short u) {
    union { unsigned int i; float f; } v; v.i = ((unsigned int)u) << 16; return v.f;
}

// ---------------------------------------------------------------------------
// 1a/1b) deterministic fp64 mean-reduction over S   (r8-proven)
// ---------------------------------------------------------------------------
__global__ void k_reduce1(const float* __restrict__ x,
                          double* __restrict__ partial) {
    int b = blockIdx.x >> 6;
    int c = blockIdx.x & 63;
    int d = threadIdx.x;
    const float* p = x + ((size_t)(b * S_ + c * 64) * D_ + d);
    double acc = 0.0;
    #pragma unroll 8
    for (int i = 0; i < 64; ++i) acc += (double)p[(size_t)i * D_];
    partial[(size_t)blockIdx.x * D_ + d] = acc;
}

__global__ void k_reduce2(const double* __restrict__ partial,
                          double* __restrict__ xsum) {
    int b = blockIdx.x;
    int d = threadIdx.x;
    double acc = 0.0;
    #pragma unroll 8
    for (int c = 0; c < 64; ++c) acc += partial[(size_t)(b * 64 + c) * D_ + d];
    xsum[b * D_ + d] = acc;
}

// ---------------------------------------------------------------------------
// 2) Router, FP64, plain top-2 (r8-proven: matches np selection)
// ---------------------------------------------------------------------------
__global__ void k_router(const double* __restrict__ xsum,
                         const float* __restrict__ Wr,
                         const float* __restrict__ br,
                         float* __restrict__ route) {
    __shared__ double lg[64];
    int t = threadIdx.x;
    int b = t >> 3, e = t & 7;
    double acc = 0.0;
    for (int d = 0; d < D_; ++d)
        acc += (xsum[b * D_ + d] * (1.0 / (double)S_)) * (double)Wr[d * E_ + e];
    lg[t] = acc + (double)br[e];
    __syncthreads();
    if (t == 0) {
        double rw[8][8];
        for (int bb = 0; bb < 8; ++bb) {
            double m = -1e300;
            for (int ee = 0; ee < 8; ++ee) m = fmax(m, lg[bb * 8 + ee]);
            double s = 0.0;
            for (int ee = 0; ee < 8; ++ee) { double p = exp(lg[bb * 8 + ee] - m); rw[bb][ee] = p; s += p; }
            for (int ee = 0; ee < 8; ++ee) rw[bb][ee] /= s;
        }
        const double capacity = 5120.0;
        double scale[8];
        for (int ee = 0; ee < 8; ++ee) {
            double load = 0.0;
            for (int bb = 0; bb < 8; ++bb) load += rw[bb][ee];
            load *= 4096.0;
            scale[ee] = load > capacity ? capacity / load : 1.0;
        }
        for (int bb = 0; bb < 8; ++bb) {
            double v[8];
            double m = -1e300;
            for (int ee = 0; ee < 8; ++ee) { v[ee] = rw[bb][ee] * scale[ee]; m = fmax(m, v[ee]); }
            double s = 0.0;
            for (int ee = 0; ee < 8; ++ee) { v[ee] = exp(v[ee] - m); s += v[ee]; }
            for (int ee = 0; ee < 8; ++ee) v[ee] /= s;
            int i1 = 0;
            for (int ee = 1; ee < 8; ++ee) if (v[ee] > v[i1]) i1 = ee;
            int i2 = (i1 == 0) ? 1 : 0;
            for (int ee = 0; ee < 8; ++ee) { if (ee == i1) continue; if (v[ee] > v[i2]) i2 = ee; }
            double d21 = v[i2] - v[i1];
            double ed = exp(d21);
            double w1 = 1.0 / (1.0 + ed);
            double w2 = ed * w1;
            route[bb * 4 + 0] = (float)i1;
            route[bb * 4 + 1] = (float)i2;
            route[bb * 4 + 2] = (float)w1;
            route[bb * 4 + 3] = (float)w2;
        }
    }
}

// ---------------------------------------------------------------------------
// 3) Batched transpose+convert: src [E][R][C] fp32 -> dst [E][C][R] bf16
// ---------------------------------------------------------------------------
__global__ void k_cvt_w(const float* __restrict__ src,
                        unsigned short* __restrict__ dst, int R, int C) {
    __shared__ float tile[32][33];
    int e = blockIdx.z;
    int cb = blockIdx.x * 32, rb = blockIdx.y * 32;
    int tx = threadIdx.x & 31, ty = threadIdx.x >> 5;
    const float* s = src + (size_t)e * R * C;
    unsigned short* d = dst + (size_t)e * R * C;
    #pragma unroll
    for (int k = 0; k < 4; ++k)
        tile[ty + 8 * k][tx] = s[(size_t)(rb + ty + 8 * k) * C + cb + tx];
    __syncthreads();
    #pragma unroll
    for (int k = 0; k < 4; ++k)
        d[(size_t)(cb + ty + 8 * k) * R + rb + tx] = f2bf(tile[tx][ty + 8 * k]);
}

// ---------------------------------------------------------------------------
// 4) Main MFMA kernel: per block = (batch, 32-token tile). 1024 x 256.
//    Per expert, per 64-wide F-block:
//      GEMM1: A = Xsb (LDS bf16, staged once), B = W1T (GLOBAL bf16 frags)
//             -> Hacc (C-layout) -> GELU*w -> Hsb (bf16 LDS, 2 barriers)
//      GEMM2: A = Hsb, B = W2T (GLOBAL bf16 frags) -> Yacc fp32 regs.
//    Epilogue: Yb fp32 LDS + b2 + residual(fp32 global) -> LN -> fp32 out.
//    MFMA 16x16x32 bf16; mappings validated by r2's 0.031 pass.
// ---------------------------------------------------------------------------
__launch_bounds__(256, 2)
__global__ void k_moe_m(const float* __restrict__ xf,
                        const unsigned short* __restrict__ W1T,  // [E][F][D]
                        const unsigned short* __restrict__ W2T,  // [E][D][F]
                        const float* __restrict__ b1,
                        const float* __restrict__ b2,
                        const float* __restrict__ gamma,
                        const float* __restrict__ beta,
                        const float* __restrict__ route,
                        float* __restrict__ out) {
    __shared__ __align__(16) unsigned short Xsb[32][264];  // bf16 X tile
    __shared__ __align__(16) unsigned short Hsb[32][72];   // bf16 H block
    __shared__ __align__(16) float Yb[32][260];            // fp32 pre-LN
    __shared__ float gbuf[256], bbuf[256];

    const int t = threadIdx.x;
    const int wv = t >> 6;            // wave 0..3
    const int lane = t & 63;
    const int g = lane >> 4;          // quad 0..3
    const int c = lane & 15;          // 0..15
    const int b = blockIdx.x & 7;     // XCD swizzle
    const int m0 = (blockIdx.x >> 3) * 32;

    gbuf[t] = gamma[t];
    bbuf[t] = beta[t];

    // ---- stage X tile [32][256] as bf16, once ----
    {
        int row = t >> 3;
        int col0 = (t & 7) * 32;
        const float* src = xf + ((size_t)(b * S_ + m0 + row) * D_ + col0);
        #pragma unroll
        for (int jg = 0; jg < 4; ++jg) {
            float4 a0 = *(const float4*)(src + jg * 8);
            float4 a1 = *(const float4*)(src + jg * 8 + 4);
            float vv[8] = { a0.x, a0.y, a0.z, a0.w, a1.x, a1.y, a1.z, a1.w };
            union { unsigned short u[8]; uint4 q; } o;
            #pragma unroll
            for (int j = 0; j < 8; ++j) o.u[j] = f2bf(vv[j]);
            *(uint4*)&Xsb[row][col0 + jg * 8] = o.q;
        }
    }

    const int e0i = (int)route[b * 4 + 0];
    const int e1i = (int)route[b * 4 + 1];
    const float rw0 = route[b * 4 + 2];
    const float rw1 = route[b * 4 + 3];
    const int eidx[2] = { e0i, e1i };
    const float wgt[2] = { rw0, rw1 };

    f32x4 Yacc[2][4];
    #pragma unroll
    for (int i = 0; i < 2; ++i)
        #pragma unroll
        for (int j = 0; j < 4; ++j)
            #pragma unroll
            for (int r = 0; r < 4; ++r) Yacc[i][j][r] = 0.f;

    __syncthreads();   // Xsb visible to all waves

    for (int sl = 0; sl < 2; ++sl) {
        const int e = eidx[sl];
        const float w = wgt[sl];
        for (int fb = 0; fb < 8; ++fb) {
            // ---- GEMM1: H[32][64] = X @ W1[:, fb*64..]; B from GLOBAL ----
            f32x4 Hacc[2];
            #pragma unroll
            for (int i = 0; i < 2; ++i)
                #pragma unroll
                for (int r = 0; r < 4; ++r) Hacc[i][r] = 0.f;
            // wave wv covers F-cols fb*64 + wv*16 + c (n = c)
            const unsigned short* w1p =
                W1T + ((size_t)(e * F_ + fb * 64 + wv * 16 + c)) * D_ + g * 8;
            #pragma unroll
            for (int kc = 0; kc < 8; ++kc) {
                bf16x8 bf = *(const bf16x8*)(w1p + kc * 32);
                bf16x8 a0 = *(const bf16x8*)&Xsb[c][kc * 32 + g * 8];
                bf16x8 a1 = *(const bf16x8*)&Xsb[16 + c][kc * 32 + g * 8];
                Hacc[0] = __builtin_amdgcn_mfma_f32_16x16x32_bf16(a0, bf, Hacc[0], 0, 0, 0);
                Hacc[1] = __builtin_amdgcn_mfma_f32_16x16x32_bf16(a1, bf, Hacc[1], 0, 0, 0);
            }

            __syncthreads();   // previous GEMM2 done reading Hsb
            // ---- GELU(+b1)*w -> Hsb[32][64] (C-layout positions) ----
            {
                float bias1 = b1[e * F_ + fb * 64 + wv * 16 + c];
                #pragma unroll
                for (int mt = 0; mt < 2; ++mt)
                    #pragma unroll
                    for (int r = 0; r < 4; ++r) {
                        int row = mt * 16 + g * 4 + r;
                        float v = Hacc[mt][r] + bias1;
                        float h = 0.5f * v * (1.0f + erff(v * 0.70710678118654752f));
                        Hsb[row][wv * 16 + c] = f2bf(w * h);
                    }
            }
            __syncthreads();   // Hsb visible

            // ---- GEMM2: Y[32][256] += Hsb @ W2[fb*64.., :]; B from GLOBAL ----
            // wave wv covers d-cols wv*64 + nt*16 + c
            const unsigned short* w2p =
                W2T + ((size_t)(e * D_ + wv * 64 + c)) * F_ + fb * 64 + g * 8;
            #pragma unroll
            for (int kc = 0; kc < 2; ++kc) {
                bf16x8 a0 = *(const bf16x8*)&Hsb[c][kc * 32 + g * 8];
                bf16x8 a1 = *(const bf16x8*)&Hsb[16 + c][kc * 32 + g * 8];
                #pragma unroll
                for (int nt = 0; nt < 4; ++nt) {
                    bf16x8 bf = *(const bf16x8*)(w2p + (size_t)(nt * 16) * F_ + kc * 32);
                    Yacc[0][nt] = __builtin_amdgcn_mfma_f32_16x16x32_bf16(a0, bf, Yacc[0][nt], 0, 0, 0);
                    Yacc[1][nt] = __builtin_amdgcn_mfma_f32_16x16x32_bf16(a1, bf, Yacc[1][nt], 0, 0, 0);
                }
            }
        }
    }

    // ---- Epilogue: Yb = Y + combined b2 + residual (all fp32) ----
    // (Yb is a distinct LDS region; no barrier needed before writing)
    #pragma unroll
    for (int nt = 0; nt < 4; ++nt) {
        int d = wv * 64 + nt * 16 + c;
        float bias2 = rw0 * b2[e0i * D_ + d] + rw1 * b2[e1i * D_ + d];
        #pragma unroll
        for (int mt = 0; mt < 2; ++mt)
            #pragma unroll
            for (int r = 0; r < 4; ++r) {
                int row = mt * 16 + g * 4 + r;
                float xr = xf[(size_t)(b * S_ + m0 + row) * D_ + d];
                Yb[row][d] = Yacc[mt][nt][r] + bias2 + xr;
            }
    }
    __syncthreads();

    // ---- LayerNorm (r8-proven): 8 threads/row, 32 elems each ----
    {
        int row = t >> 3, q = t & 7;
        float sum = 0.f, sq = 0.f;
        #pragma unroll
        for (int j = 0; j < 32; ++j) {
            float v = Yb[row][q * 32 + j];
            sum += v; sq += v * v;
        }
        sum += __shfl_xor(sum, 1); sq += __shfl_xor(sq, 1);
        sum += __shfl_xor(sum, 2); sq += __shfl_xor(sq, 2);
        sum += __shfl_xor(sum, 4); sq += __shfl_xor(sq, 4);
        float mu = sum * (1.0f / 256.0f);
        float var = sq * (1.0f / 256.0f) - mu * mu;
        float rstd = rsqrtf(var + 1e-5f);
        float* op = out + (size_t)(b * S_ + m0 + row) * D_ + q * 32;
        #pragma unroll
        for (int j4 = 0; j4 < 32; j4 += 4) {
            float4 v = *(const float4*)&Yb[row][q * 32 + j4];
            int db = q * 32 + j4;
            float4 o;
            o.x = (v.x - mu) * rstd * gbuf[db + 0] + bbuf[db + 0];
            o.y = (v.y - mu) * rstd * gbuf[db + 1] + bbuf[db + 1];
            o.z = (v.z - mu) * rstd * gbuf[db + 2] + bbuf[db + 2];
            o.w = (v.w - mu) * rstd * gbuf[db + 3] + bbuf[db + 3];
            *(float4*)(op + j4) = o;
        }
    }
}

// ---------------------------------------------------------------------------
extern "C" void kernel_launch(void* const* d_in, const int* in_sizes, int n_in,
                              void* d_out, int out_size, void* d_ws, size_t ws_size,
                              hipStream_t stream) {
    const float* x     = (const float*)d_in[0];
    const float* Wr    = (const float*)d_in[1];
    const float* br    = (const float*)d_in[2];
    const float* W1    = (const float*)d_in[3];
    const float* b1    = (const float*)d_in[4];
    const float* W2    = (const float*)d_in[5];
    const float* b2    = (const float*)d_in[6];
    const float* gamma = (const float*)d_in[7];
    const float* beta  = (const float*)d_in[8];
    float* out = (float*)d_out;

    char* ws = (char*)d_ws;
    double* partial = (double*)ws;                               // 1 MB
    double* xsum  = (double*)(ws + 1048576);                     // 16 KB
    float* route  = (float*)(ws + 1064960);                      // 128 B
    unsigned short* W1T = (unsigned short*)(ws + 1081344);       // 2 MB [E][F][D]
    unsigned short* W2T = (unsigned short*)(ws + 3178496);       // 2 MB [E][D][F]
    // total ws usage: ~5.1 MB

    hipLaunchKernelGGL(k_reduce1, dim3(512), dim3(256), 0, stream, x, partial);
    hipLaunchKernelGGL(k_reduce2, dim3(8), dim3(256), 0, stream, partial, xsum);
    hipLaunchKernelGGL(k_router, dim3(1), dim3(64), 0, stream, xsum, Wr, br, route);
    hipLaunchKernelGGL(k_cvt_w, dim3(16, 8, 8), dim3(256), 0, stream, W1, W1T, 256, 512);
    hipLaunchKernelGGL(k_cvt_w, dim3(8, 16, 8), dim3(256), 0, stream, W2, W2T, 512, 256);
    hipLaunchKernelGGL(k_moe_m, dim3(1024), dim3(256), 0, stream,
                       x, W1T, W2T, b1, b2, gamma, beta, route, out);
}